// Round 1
// baseline (12580.756 us; speedup 1.0000x reference)
//
#include <hip/hip_runtime.h>

#define M 256     // n_hos * n_types (rows of S)
#define N 4096    // n_structs (cols of S)
#define NIT 200   // PDHG iterations
#define PIT 30    // power iterations

// ---------------- build: per-column / per-row nnz counts ----------------
__global__ void k_colcnt(const float* __restrict__ S, int* __restrict__ col_cnt){
  int j = blockIdx.x*256 + threadIdx.x;
  int c = 0;
  for (int i = 0; i < M; ++i) c += (S[i*N + j] != 0.0f) ? 1 : 0;
  col_cnt[j] = c;
}

__global__ void k_rowcnt(const float* __restrict__ S, int* __restrict__ row_cnt){
  int i = threadIdx.x;
  int c = 0;
  for (int j = 0; j < N; ++j) c += (S[i*N + j] != 0.0f) ? 1 : 0;
  row_cnt[i] = c;
}

// ---------------- deterministic rank sort by (cnt, index) ----------------
// Each thread computes its column's rank and exclusive nnz-prefix in one pass.
__global__ void k_sortcol(const int* __restrict__ col_cnt,
                          int* __restrict__ col_perm, int* __restrict__ col_ptr){
  int j = blockIdx.x*256 + threadIdx.x;
  int cj = col_cnt[j];
  int rank = 0, pre = 0;
  for (int jj = 0; jj < N; ++jj){
    int c = col_cnt[jj];
    bool less = (c < cj) || (c == cj && jj < j);
    rank += less ? 1 : 0;
    pre  += less ? c : 0;
  }
  col_perm[rank] = j;   // sorted slot -> original column
  col_ptr[rank]  = pre; // CSC start for that slot
}

__global__ void k_sortrow(const int* __restrict__ row_cnt,
                          int* __restrict__ row_perm, int* __restrict__ row_ptr){
  int i = threadIdx.x;
  int ci = row_cnt[i];
  int rank = 0, pre = 0;
  for (int ii = 0; ii < M; ++ii){
    int c = row_cnt[ii];
    bool less = (c < ci) || (c == ci && ii < i);
    rank += less ? 1 : 0;
    pre  += less ? c : 0;
  }
  row_perm[rank] = i;
  row_ptr[rank]  = pre;
}

// ---------------- fill CSC / CSR (indices pre-scaled to byte offsets) ----
__global__ void k_fillcsc(const float* __restrict__ S, const int* __restrict__ col_perm,
                          const int* __restrict__ col_ptr, unsigned short* __restrict__ csc){
  int s = blockIdx.x*256 + threadIdx.x;   // sorted slot
  int j = col_perm[s];
  int pos = col_ptr[s];
  for (int i = 0; i < M; ++i){
    if (S[i*N + j] != 0.0f) csc[pos++] = (unsigned short)(i*4);  // byte offset into y/u
  }
}

__global__ void k_fillcsr(const float* __restrict__ S, const int* __restrict__ row_perm,
                          const int* __restrict__ row_ptr, unsigned short* __restrict__ csr){
  int r = threadIdx.x;                    // sorted slot
  int i = row_perm[r];
  int pos = row_ptr[r];
  for (int j = 0; j < N; ++j){
    if (S[i*N + j] != 0.0f) csr[pos++] = (unsigned short)(j*4);  // byte offset into z/v
  }
}

// ---------------- power iteration: tau = sigma = 0.9 / ||S||_2 ----------
__global__ __launch_bounds__(256) void k_power(
    const unsigned short* __restrict__ csc, const unsigned short* __restrict__ csr,
    const int* __restrict__ col_perm, const int* __restrict__ col_ptr, const int* __restrict__ col_cnt,
    const int* __restrict__ row_perm, const int* __restrict__ row_ptr, const int* __restrict__ row_cnt,
    float* __restrict__ tauw)
{
  __shared__ float v_s[N];
  __shared__ float u_s[M];
  __shared__ float red[256];
  const int tid = threadIdx.x;

  int cj[16], cb[16], ce[16];
  #pragma unroll
  for (int k = 0; k < 16; ++k){
    int s = tid + 256*k;
    cj[k] = col_perm[s];
    cb[k] = col_ptr[s];
    ce[k] = cb[k] + col_cnt[cj[k]];
    v_s[s] = 1.0f;                 // v0 = ones
  }
  const int rid = row_perm[tid];
  const int rb  = row_ptr[tid];
  const int re  = rb + row_cnt[rid];
  __syncthreads();

  for (int it = 0; it < PIT; ++it){
    // u = S v
    float su = 0.0f;
    for (int p = rb; p < re; ++p) su += *(const float*)((const char*)v_s + csr[p]);
    u_s[rid] = su;
    __syncthreads();
    // t = S^T u ; accumulate ||t||^2
    float t[16]; float ls = 0.0f;
    #pragma unroll
    for (int k = 0; k < 16; ++k){
      float a = 0.0f;
      for (int p = cb[k]; p < ce[k]; ++p) a += *(const float*)((const char*)u_s + csc[p]);
      t[k] = a; ls += a*a;
    }
    red[tid] = ls; __syncthreads();
    for (int sd = 128; sd > 0; sd >>= 1){ if (tid < sd) red[tid] += red[tid+sd]; __syncthreads(); }
    float inv = 1.0f / sqrtf(red[0]);
    #pragma unroll
    for (int k = 0; k < 16; ++k) v_s[cj[k]] = t[k] * inv;   // v = t / ||t||
    __syncthreads();
  }
  // L = ||S v||  (== sqrt(v . S^T S v))
  float su = 0.0f;
  for (int p = rb; p < re; ++p) su += *(const float*)((const char*)v_s + csr[p]);
  red[tid] = su*su; __syncthreads();
  for (int sd = 128; sd > 0; sd >>= 1){ if (tid < sd) red[tid] += red[tid+sd]; __syncthreads(); }
  if (tid == 0) tauw[0] = 0.9f / sqrtf(red[0]);
}

// ---------------- persistent PDHG: one block per batch element ----------
__global__ __launch_bounds__(512, 2) void k_main(
    const float* __restrict__ X,
    const unsigned short* __restrict__ csc, const unsigned short* __restrict__ csr,
    const int* __restrict__ col_perm, const int* __restrict__ col_ptr, const int* __restrict__ col_cnt,
    const int* __restrict__ row_perm, const int* __restrict__ row_ptr, const int* __restrict__ row_cnt,
    const float* __restrict__ tauw, float* __restrict__ out)
{
  __shared__ float z_s[N];      // 2*x_new - x_old, by actual column id
  __shared__ float y_s[M];      // dual, by actual row id
  __shared__ float part[512];   // row half-sums
  const int tid = threadIdx.x;
  const int b   = blockIdx.x;
  const float tau   = tauw[0];
  const float sigma = tau;

  // 8 sorted column slots per thread (lanes get similar nnz counts)
  int cj[8], cb[8], ce[8];
  float x[8];
  #pragma unroll
  for (int k = 0; k < 8; ++k){
    int s = tid + 512*k;
    cj[k] = col_perm[s];
    cb[k] = col_ptr[s];
    ce[k] = cb[k] + col_cnt[cj[k]];
    x[k]  = 0.0f;
  }
  // dual rows: 2 threads per row, each handles half the nnz list
  const int r   = tid & (M-1);
  const int hh  = tid >> 8;           // 0 or 1
  const int rid = row_perm[r];
  const int rb0  = row_ptr[r];
  const int rlen = row_cnt[rid];
  const int mid  = rb0 + (rlen >> 1);
  const int gb = hh ? mid : rb0;
  const int ge = hh ? (rb0 + rlen) : mid;
  float bi = 0.0f, yv = 0.0f;
  if (tid < M){
    bi = X[b*M + rid];
    y_s[tid] = 0.0f;
  }
  __syncthreads();

  for (int it = 0; it < NIT; ++it){
    // primal: x+ = max(x + tau*(1 - y S), 0);  z = 2 x+ - x
    #pragma unroll
    for (int k = 0; k < 8; ++k){
      float acc = 0.0f;
      for (int p = cb[k]; p < ce[k]; ++p) acc += *(const float*)((const char*)y_s + csc[p]);
      float xo = x[k];
      float xn = fmaxf(xo + tau*(1.0f - acc), 0.0f);
      z_s[cj[k]] = 2.0f*xn - xo;
      x[k] = xn;
    }
    __syncthreads();
    // dual: y+ = max(y + sigma*(z S^T - b), 0)
    {
      float acc = 0.0f;
      for (int p = gb; p < ge; ++p) acc += *(const float*)((const char*)z_s + csr[p]);
      part[tid] = acc;
    }
    __syncthreads();
    if (tid < M){
      float full = part[tid] + part[tid + 256];
      yv = fmaxf(yv + sigma*(full - bi), 0.0f);
      y_s[rid] = yv;
    }
    __syncthreads();
  }

  #pragma unroll
  for (int k = 0; k < 8; ++k) out[b*N + cj[k]] = x[k];
}

// ---------------- launcher ----------------
extern "C" void kernel_launch(void* const* d_in, const int* in_sizes, int n_in,
                              void* d_out, int out_size, void* d_ws, size_t ws_size,
                              hipStream_t stream)
{
  const float* X = (const float*)d_in[0];   // [B, 16, 16] -> b vectors
  const float* S = (const float*)d_in[1];   // [M, N]
  float* out = (float*)d_out;               // [B, N] fp32
  const int B = in_sizes[0] / M;

  char* w = (char*)d_ws;
  int* col_cnt  = (int*)w; w += N*sizeof(int);
  int* col_perm = (int*)w; w += N*sizeof(int);
  int* col_ptr  = (int*)w; w += N*sizeof(int);
  int* row_cnt  = (int*)w; w += M*sizeof(int);
  int* row_perm = (int*)w; w += M*sizeof(int);
  int* row_ptr  = (int*)w; w += M*sizeof(int);
  float* tauw   = (float*)w; w += 256;
  unsigned short* csc = (unsigned short*)w; w += 65536*sizeof(unsigned short);
  unsigned short* csr = (unsigned short*)w;

  k_colcnt <<<N/256, 256, 0, stream>>>(S, col_cnt);
  k_rowcnt <<<1,     M,   0, stream>>>(S, row_cnt);
  k_sortcol<<<N/256, 256, 0, stream>>>(col_cnt, col_perm, col_ptr);
  k_sortrow<<<1,     M,   0, stream>>>(row_cnt, row_perm, row_ptr);
  k_fillcsc<<<N/256, 256, 0, stream>>>(S, col_perm, col_ptr, csc);
  k_fillcsr<<<1,     M,   0, stream>>>(S, row_perm, row_ptr, csr);
  k_power  <<<1,     256, 0, stream>>>(csc, csr, col_perm, col_ptr, col_cnt,
                                       row_perm, row_ptr, row_cnt, tauw);
  k_main   <<<B,     512, 0, stream>>>(X, csc, csr, col_perm, col_ptr, col_cnt,
                                       row_perm, row_ptr, row_cnt, tauw, out);
}

// Round 3
// 1396.454 us; speedup vs baseline: 9.0091x; 9.0091x over previous
//
#include <hip/hip_runtime.h>

#define M 256     // rows of S (n_hos*n_types)
#define N 4096    // cols of S (n_structs)
#define NIT 200   // PDHG iterations
#define PIT 30    // power iterations
#define CSRCAP 131072

// dummy byte-offsets (float2 slots): y_s[256], z_s[4096]
#define YDUMMY (256*8)
#define ZDUMMY (4096*8)

// ---------------- counts ----------------
__global__ void k_colcnt(const float* __restrict__ S, int* __restrict__ col_cnt){
  int j = blockIdx.x*256 + threadIdx.x;          // coalesced: lanes = adjacent cols
  int c = 0;
  for (int i = 0; i < M; ++i) c += (S[i*N + j] != 0.0f) ? 1 : 0;
  col_cnt[j] = c;
}

__global__ void k_rowcnt(const float* __restrict__ S, int* __restrict__ row_cnt){
  int wid = blockIdx.x*(blockDim.x>>6) + (threadIdx.x>>6);  // one wave per row
  int l = threadIdx.x & 63;
  if (wid >= M) return;
  int cnt = 0;
  for (int jc = 0; jc < N/64; ++jc){
    float v = S[wid*N + jc*64 + l];
    unsigned long long mask = __ballot(v != 0.0f);
    cnt += __popcll(mask);
  }
  if (l == 0) row_cnt[wid] = cnt;
}

// ---------------- deterministic rank sort by (cnt, index) ----------------
__global__ void k_sortcol(const int* __restrict__ col_cnt,
                          int* __restrict__ col_perm, int* __restrict__ col_rank){
  int j = blockIdx.x*256 + threadIdx.x;
  int cj = col_cnt[j];
  int rank = 0;
  for (int jj = 0; jj < N; ++jj){
    int c = col_cnt[jj];
    rank += ((c < cj) || (c == cj && jj < j)) ? 1 : 0;
  }
  col_perm[rank] = j;
  col_rank[j] = rank;
}

__global__ void k_sortrow(const int* __restrict__ row_cnt,
                          int* __restrict__ row_perm, int* __restrict__ row_ptr){
  int i = threadIdx.x;
  int ci = row_cnt[i];
  int rank = 0, pre = 0;
  for (int ii = 0; ii < M; ++ii){
    int c = row_cnt[ii];
    bool less = (c < ci) || (c == ci && ii < i);
    rank += less ? 1 : 0;
    pre  += less ? c : 0;
  }
  row_perm[rank] = i;
  row_ptr[rank]  = pre;
}

// ---------------- CSR fill (sorted-row order, ballot/popc, coalesced) ----
__global__ void k_fillcsr(const float* __restrict__ S, const int* __restrict__ row_perm,
                          const int* __restrict__ row_ptr, unsigned short* __restrict__ csr){
  int rr = blockIdx.x*(blockDim.x>>6) + (threadIdx.x>>6);  // sorted slot, one wave each
  int l = threadIdx.x & 63;
  if (rr >= M) return;
  int i = row_perm[rr];
  int pos = row_ptr[rr];
  for (int jc = 0; jc < N/64; ++jc){
    float v = S[i*N + jc*64 + l];
    unsigned long long mask = __ballot(v != 0.0f);
    if (v != 0.0f){
      int off = __popcll(mask & ((1ull << l) - 1ull));
      int p = pos + off;
      if (p < CSRCAP) csr[p] = (unsigned short)((jc*64 + l)*8);
    }
    pos += __popcll(mask);
  }
}

// ---------------- wave-trip counts + base offsets (TRIP units) ----------
__global__ void k_trips(const int* __restrict__ col_cnt, const int* __restrict__ col_perm,
                        const int* __restrict__ row_cnt, const int* __restrict__ row_perm,
                        int* __restrict__ pT4, int* __restrict__ pB4,
                        int* __restrict__ dT4, int* __restrict__ dB4){
  int tid = threadIdx.x;
  if (tid < 64){                       // kw = k*16 + w
    int k = tid >> 4, w = tid & 15;
    int mx = 0;
    for (int l = 0; l < 64; ++l){
      int s = 64*w + l + 1024*k;
      int c = col_cnt[col_perm[s]];
      mx = max(mx, c);
    }
    pT4[tid] = min((mx + 3) >> 2, 16);
  } else if (tid < 80){
    int w = tid - 64;
    int mx = 0;
    for (int l = 0; l < 64; ++l){
      int t = 64*w + l;
      int r = t & 255, q = t >> 8;
      int len = row_cnt[row_perm[r]];
      int qs = (len*q) >> 2, qe = (len*(q+1)) >> 2;
      mx = max(mx, qe - qs);
    }
    dT4[w] = min((mx + 3) >> 2, 80);
  }
  __syncthreads();
  if (tid == 0){
    int acc = 0;
    for (int i = 0; i < 64; ++i){ pB4[i] = acc; acc += pT4[i]; }   // TRIP units
    acc = 0;
    for (int i = 0; i < 16; ++i){ dB4[i] = acc; acc += dT4[i]; }   // TRIP units
  }
}

// ---------------- primal stream fill (transposed, padded) ----------------
// slot for (group kw, trip c, lane l) = (pB4[kw] + c)*64 + l  (ushort4 units)
__global__ void k_fillp(const float* __restrict__ S, const int* __restrict__ col_rank,
                        const int* __restrict__ pT4, const int* __restrict__ pB4,
                        unsigned short* __restrict__ pstream){
  int j = blockIdx.x*256 + threadIdx.x;
  int s = col_rank[j];
  int k = s >> 10, rem = s & 1023, w = rem >> 6, l = rem & 63;
  int kw = k*16 + w;
  int base = pB4[kw];
  int cap = pT4[kw]*4;
  int t = 0;
  for (int i = 0; i < M && t < cap; ++i){
    if (S[i*N + j] != 0.0f){
      pstream[((base + (t>>2))*64 + l)*4 + (t&3)] = (unsigned short)(i*8);
      ++t;
    }
  }
  for (; t < cap; ++t)
    pstream[((base + (t>>2))*64 + l)*4 + (t&3)] = (unsigned short)YDUMMY;
}

// ---------------- dual stream fill (transposed, padded) ----------------
__global__ void k_filld(const unsigned short* __restrict__ csr,
                        const int* __restrict__ row_cnt, const int* __restrict__ row_perm,
                        const int* __restrict__ row_ptr,
                        const int* __restrict__ dT4, const int* __restrict__ dB4,
                        unsigned short* __restrict__ dstream){
  int tid = blockIdx.x*256 + threadIdx.x;   // 1024 threads total, same mapping as k_main
  int w = tid >> 6, l = tid & 63;
  int r = tid & 255, q = tid >> 8;
  int len = row_cnt[row_perm[r]];
  int rb = row_ptr[r];
  int qs = (len*q) >> 2, qe = (len*(q+1)) >> 2;
  int base = dB4[w];
  int cap = dT4[w]*4;
  int qlen = qe - qs; if (qlen > cap) qlen = cap;
  int t = 0;
  for (; t < qlen; ++t)
    dstream[((base + (t>>2))*64 + l)*4 + (t&3)] = csr[rb + qs + t];
  for (; t < cap; ++t)
    dstream[((base + (t>>2))*64 + l)*4 + (t&3)] = (unsigned short)ZDUMMY;
}

// ---------------- power iteration: tau = 0.9 / ||S||_2 ----------------
__global__ __launch_bounds__(1024) void k_power(
    const ushort4* __restrict__ pstream, const ushort4* __restrict__ dstream,
    const int* __restrict__ col_perm, const int* __restrict__ row_perm,
    const int* __restrict__ pT4, const int* __restrict__ pB4,
    const int* __restrict__ dT4, const int* __restrict__ dB4,
    float* __restrict__ tauw)
{
  __shared__ float2 v_s[N+1];
  __shared__ float2 u_s[M+1];
  __shared__ float2 part[1024];
  const int tid = threadIdx.x, w = tid >> 6, l = tid & 63;

  int cj[4], pb[4], pt[4];
  #pragma unroll
  for (int k = 0; k < 4; ++k){
    int kw = k*16 + w;
    pb[k] = pB4[kw]; pt[k] = pT4[kw];
    cj[k] = col_perm[tid + 1024*k];
    v_s[cj[k]] = make_float2(1.0f, 1.0f);
  }
  const int r = tid & 255;
  const int rid = row_perm[r];
  const int db = dB4[w], dt = dT4[w];
  if (tid == 0){ v_s[N] = make_float2(0,0); u_s[M] = make_float2(0,0); }
  __syncthreads();

  for (int it = 0; it < PIT; ++it){
    // u = S v
    float ax = 0.0f;
    for (int c = 0; c < dt; ++c){
      ushort4 ix = dstream[(db + c)*64 + l];
      float2 v0 = *(const float2*)((const char*)v_s + ix.x);
      float2 v1 = *(const float2*)((const char*)v_s + ix.y);
      float2 v2 = *(const float2*)((const char*)v_s + ix.z);
      float2 v3 = *(const float2*)((const char*)v_s + ix.w);
      ax += (v0.x + v1.x) + (v2.x + v3.x);
    }
    part[tid] = make_float2(ax, 0.0f);
    __syncthreads();
    if (tid < M){
      float f = ((part[tid].x + part[tid+256].x) + (part[tid+512].x + part[tid+768].x));
      u_s[rid] = make_float2(f, f);
    }
    __syncthreads();
    // t = S^T u ; normalize
    float tx[4]; float ls = 0.0f;
    #pragma unroll
    for (int k = 0; k < 4; ++k){
      float a = 0.0f;
      for (int c = 0; c < pt[k]; ++c){
        ushort4 ix = pstream[(pb[k] + c)*64 + l];
        float2 v0 = *(const float2*)((const char*)u_s + ix.x);
        float2 v1 = *(const float2*)((const char*)u_s + ix.y);
        float2 v2 = *(const float2*)((const char*)u_s + ix.z);
        float2 v3 = *(const float2*)((const char*)u_s + ix.w);
        a += (v0.x + v1.x) + (v2.x + v3.x);
      }
      tx[k] = a; ls += a*a;
    }
    part[tid].x = ls;
    __syncthreads();
    for (int sd = 512; sd > 0; sd >>= 1){
      if (tid < sd) part[tid].x += part[tid+sd].x;
      __syncthreads();
    }
    float inv = 1.0f / sqrtf(part[0].x);
    __syncthreads();
    #pragma unroll
    for (int k = 0; k < 4; ++k) v_s[cj[k]] = make_float2(tx[k]*inv, tx[k]*inv);
    __syncthreads();
  }
  // L = ||S v||
  float ax = 0.0f;
  for (int c = 0; c < dt; ++c){
    ushort4 ix = dstream[(db + c)*64 + l];
    float2 v0 = *(const float2*)((const char*)v_s + ix.x);
    float2 v1 = *(const float2*)((const char*)v_s + ix.y);
    float2 v2 = *(const float2*)((const char*)v_s + ix.z);
    float2 v3 = *(const float2*)((const char*)v_s + ix.w);
    ax += (v0.x + v1.x) + (v2.x + v3.x);
  }
  part[tid] = make_float2(ax, 0.0f);
  __syncthreads();
  float full = 0.0f;
  if (tid < M)
    full = ((part[tid].x + part[tid+256].x) + (part[tid+512].x + part[tid+768].x));
  __syncthreads();
  part[tid].x = full*full;
  __syncthreads();
  for (int sd = 512; sd > 0; sd >>= 1){
    if (tid < sd) part[tid].x += part[tid+sd].x;
    __syncthreads();
  }
  if (tid == 0) tauw[0] = 0.9f / sqrtf(part[0].x);
}

// ---------------- persistent PDHG: one block per 2 batch elements --------
__global__ __launch_bounds__(1024) void k_main(
    const float* __restrict__ X,
    const ushort4* __restrict__ pstream, const ushort4* __restrict__ dstream,
    const int* __restrict__ col_perm, const int* __restrict__ row_perm,
    const int* __restrict__ pT4, const int* __restrict__ pB4,
    const int* __restrict__ dT4, const int* __restrict__ dB4,
    const float* __restrict__ tauw, float* __restrict__ out)
{
  __shared__ float2 z_s[N+1];
  __shared__ float2 y_s[M+1];
  __shared__ float2 part[1024];
  const int tid = threadIdx.x, w = tid >> 6, l = tid & 63;
  const int b0 = blockIdx.x * 2;
  const float tau = tauw[0];
  const float sigma = tau;

  int cj[4], pb[4], pt[4];
  float2 x[4];
  #pragma unroll
  for (int k = 0; k < 4; ++k){
    int kw = k*16 + w;
    pb[k] = pB4[kw]; pt[k] = pT4[kw];
    cj[k] = col_perm[tid + 1024*k];
    x[k] = make_float2(0.0f, 0.0f);
  }
  const int r = tid & 255;
  const int rid = row_perm[r];
  const int db = dB4[w], dt = dT4[w];
  float2 bi = make_float2(0,0), yv = make_float2(0,0);
  if (tid < M){
    bi.x = X[b0*M + rid];
    bi.y = X[b0*M + M + rid];
    y_s[rid] = make_float2(0,0);
  }
  if (tid == 256) y_s[M] = make_float2(0,0);
  if (tid == 257) z_s[N] = make_float2(0,0);
  __syncthreads();

  for (int it = 0; it < NIT; ++it){
    // primal: x+ = max(x + tau*(1 - y S), 0); z = 2 x+ - x
    #pragma unroll
    for (int k = 0; k < 4; ++k){
      float ax = 0.0f, ay = 0.0f;
      for (int c = 0; c < pt[k]; ++c){
        ushort4 ix = pstream[(pb[k] + c)*64 + l];
        float2 v0 = *(const float2*)((const char*)y_s + ix.x);
        float2 v1 = *(const float2*)((const char*)y_s + ix.y);
        float2 v2 = *(const float2*)((const char*)y_s + ix.z);
        float2 v3 = *(const float2*)((const char*)y_s + ix.w);
        ax += (v0.x + v1.x) + (v2.x + v3.x);
        ay += (v0.y + v1.y) + (v2.y + v3.y);
      }
      float2 xo = x[k];
      float xnx = fmaxf(xo.x + tau*(1.0f - ax), 0.0f);
      float xny = fmaxf(xo.y + tau*(1.0f - ay), 0.0f);
      z_s[cj[k]] = make_float2(2.0f*xnx - xo.x, 2.0f*xny - xo.y);
      x[k] = make_float2(xnx, xny);
    }
    __syncthreads();
    // dual partial sums: quarter-rows
    {
      float ax = 0.0f, ay = 0.0f;
      for (int c = 0; c < dt; ++c){
        ushort4 ix = dstream[(db + c)*64 + l];
        float2 v0 = *(const float2*)((const char*)z_s + ix.x);
        float2 v1 = *(const float2*)((const char*)z_s + ix.y);
        float2 v2 = *(const float2*)((const char*)z_s + ix.z);
        float2 v3 = *(const float2*)((const char*)z_s + ix.w);
        ax += (v0.x + v1.x) + (v2.x + v3.x);
        ay += (v0.y + v1.y) + (v2.y + v3.y);
      }
      part[tid] = make_float2(ax, ay);
    }
    __syncthreads();
    if (tid < M){
      float2 p0 = part[tid], p1 = part[tid+256], p2 = part[tid+512], p3 = part[tid+768];
      float fx = (p0.x + p1.x) + (p2.x + p3.x);
      float fy = (p0.y + p1.y) + (p2.y + p3.y);
      yv.x = fmaxf(yv.x + sigma*(fx - bi.x), 0.0f);
      yv.y = fmaxf(yv.y + sigma*(fy - bi.y), 0.0f);
      y_s[rid] = yv;
    }
    __syncthreads();
  }

  #pragma unroll
  for (int k = 0; k < 4; ++k){
    out[(size_t)b0*N + cj[k]]       = x[k].x;
    out[(size_t)(b0+1)*N + cj[k]]   = x[k].y;
  }
}

// ---------------- launcher ----------------
extern "C" void kernel_launch(void* const* d_in, const int* in_sizes, int n_in,
                              void* d_out, int out_size, void* d_ws, size_t ws_size,
                              hipStream_t stream)
{
  const float* X = (const float*)d_in[0];   // [B, 16, 16] -> b
  const float* S = (const float*)d_in[1];   // [M, N]
  float* out = (float*)d_out;               // [B, N] fp32
  const int B = in_sizes[0] / M;            // 512

  char* p = (char*)d_ws;
  auto alloc = [&](size_t bytes)->char*{
    char* q = p; p += (bytes + 255) & ~size_t(255); return q;
  };
  int* col_cnt  = (int*)alloc(N*sizeof(int));
  int* col_perm = (int*)alloc(N*sizeof(int));
  int* col_rank = (int*)alloc(N*sizeof(int));
  int* row_cnt  = (int*)alloc(M*sizeof(int));
  int* row_perm = (int*)alloc(M*sizeof(int));
  int* row_ptr  = (int*)alloc(M*sizeof(int));
  int* pT4      = (int*)alloc(64*sizeof(int));
  int* pB4      = (int*)alloc(64*sizeof(int));
  int* dT4      = (int*)alloc(16*sizeof(int));
  int* dB4      = (int*)alloc(16*sizeof(int));
  float* tauw   = (float*)alloc(256);
  unsigned short* csr     = (unsigned short*)alloc(CSRCAP*sizeof(unsigned short));
  unsigned short* pstream = (unsigned short*)alloc(65536ull*8);  // <= 64 groups * 16 trips * 64 lanes
  unsigned short* dstream = (unsigned short*)alloc(81920ull*8);  // <= 16 waves * 80 trips * 64 lanes

  k_colcnt <<<N/256, 256, 0, stream>>>(S, col_cnt);
  k_rowcnt <<<16, 1024, 0, stream>>>(S, row_cnt);
  k_sortcol<<<N/256, 256, 0, stream>>>(col_cnt, col_perm, col_rank);
  k_sortrow<<<1, M, 0, stream>>>(row_cnt, row_perm, row_ptr);
  k_fillcsr<<<16, 1024, 0, stream>>>(S, row_perm, row_ptr, csr);
  k_trips  <<<1, 256, 0, stream>>>(col_cnt, col_perm, row_cnt, row_perm, pT4, pB4, dT4, dB4);
  k_fillp  <<<N/256, 256, 0, stream>>>(S, col_rank, pT4, pB4, pstream);
  k_filld  <<<4, 256, 0, stream>>>(csr, row_cnt, row_perm, row_ptr, dT4, dB4, dstream);
  k_power  <<<1, 1024, 0, stream>>>((const ushort4*)pstream, (const ushort4*)dstream,
                                    col_perm, row_perm, pT4, pB4, dT4, dB4, tauw);
  k_main   <<<B/2, 1024, 0, stream>>>(X, (const ushort4*)pstream, (const ushort4*)dstream,
                                      col_perm, row_perm, pT4, pB4, dT4, dB4, tauw, out);
}